// Round 4
// baseline (5003.550 us; speedup 1.0000x reference)
//
#include <hip/hip_runtime.h>
#include <hip/hip_bf16.h>

#define NN 100000
#define EE 1600000
#define ET (EE + NN)

typedef unsigned short ushort_t;
typedef short short8 __attribute__((ext_vector_type(8)));
typedef float f32x4 __attribute__((ext_vector_type(4)));

static __device__ __forceinline__ float b2f(unsigned short u) {
    return __uint_as_float(((unsigned int)u) << 16);
}
static __device__ __forceinline__ unsigned short f2b(float f) {
    unsigned int x = __float_as_uint(f);
    return (unsigned short)((x + 0x7fffu + ((x >> 16) & 1u)) >> 16);
}

// ---------------- fp32->bf16 transpose: W1 [512,64] -> W1T [64,512]; W2 [64,128] -> W2T [128,64]
__global__ __launch_bounds__(256) void ktrans(const float* __restrict__ W1,
                                              const float* __restrict__ W2,
                                              ushort_t* __restrict__ W1T,
                                              ushort_t* __restrict__ W2T) {
    int tid = blockIdx.x * 256 + threadIdx.x;
    if (tid < 32768) {
        int k = tid >> 6, c = tid & 63;
        W1T[c * 512 + k] = f2b(W1[tid]);
    } else if (tid < 40960) {
        int t = tid - 32768;
        int k = t >> 7, c = t & 127;
        W2T[c * 64 + k] = f2b(W2[t]);
    }
}

// ---------------- GEMM1: h1[N,64] = x[N,512] @ W1  (fp32 x -> bf16 MFMA, fp32 acc)
__global__ __launch_bounds__(256) void kgemm1(const float* __restrict__ x,
                                              const ushort_t* __restrict__ w1t,
                                              ushort_t* __restrict__ h1) {
    __shared__ __align__(16) ushort_t xs[64][136];
    const int tid = threadIdx.x;
    const int wid = tid >> 6, lane = tid & 63;
    const int l15 = lane & 15, qq = lane >> 4;
    const int row0 = blockIdx.x * 64;
    f32x4 acc[4];
#pragma unroll
    for (int i = 0; i < 4; ++i) acc[i] = (f32x4)0.f;
    for (int kc = 0; kc < 4; ++kc) {
        // stage 64 rows x 128 cols (fp32) -> bf16 LDS tile; coalesced float4 loads
        float4 f[8];
#pragma unroll
        for (int i = 0; i < 8; ++i) {
            int f4i = tid + 256 * i;         // 0..2047
            int rr = f4i >> 5;               // row in tile
            int cc = f4i & 31;               // float4 within row
            long gr = (long)min(row0 + rr, NN - 1);
            f[i] = *(const float4*)(x + gr * 512 + kc * 128 + cc * 4);
        }
        __syncthreads();
#pragma unroll
        for (int i = 0; i < 8; ++i) {
            int f4i = tid + 256 * i;
            int rr = f4i >> 5, cc = f4i & 31;
            uint2 uu;
            uu.x = ((unsigned)f2b(f[i].y) << 16) | f2b(f[i].x);
            uu.y = ((unsigned)f2b(f[i].w) << 16) | f2b(f[i].z);
            *(uint2*)&xs[rr][cc * 4] = uu;
        }
        __syncthreads();
#pragma unroll
        for (int ks = 0; ks < 4; ++ks) {
            short8 b = *(const short8*)(w1t + (size_t)(wid * 16 + l15) * 512 + kc * 128 + ks * 32 + qq * 8);
#pragma unroll
            for (int mt = 0; mt < 4; ++mt) {
                short8 a = *(const short8*)&xs[mt * 16 + l15][ks * 32 + qq * 8];
                acc[mt] = __builtin_amdgcn_mfma_f32_16x16x32_bf16(a, b, acc[mt], 0, 0, 0);
            }
        }
    }
#pragma unroll
    for (int mt = 0; mt < 4; ++mt) {
        int node = row0 + mt * 16 + qq * 4;
#pragma unroll
        for (int rr = 0; rr < 4; ++rr) {
            if (node + rr < NN)
                h1[(size_t)(node + rr) * 64 + wid * 16 + l15] = f2b(acc[mt][rr]);
        }
    }
}

// ---------------- GEMM2: h2[N,128] = hin[N,64] @ W2  (bf16 in/out)
__global__ __launch_bounds__(256) void kgemm2(const ushort_t* __restrict__ hin,
                                              const ushort_t* __restrict__ w2t,
                                              ushort_t* __restrict__ h2) {
    __shared__ __align__(16) ushort_t xs[64][72];
    const int tid = threadIdx.x;
    const int wid = tid >> 6, lane = tid & 63;
    const int l15 = lane & 15, qq = lane >> 4;
    const int row0 = blockIdx.x * 64;
    const int r = tid >> 2, seg = tid & 3;
    const long grow = (long)min(row0 + r, NN - 1);
    const uint4* gp = (const uint4*)(hin + grow * 64 + seg * 16);
    uint4 v0 = gp[0], v1 = gp[1];
    uint4* lp = (uint4*)&xs[r][seg * 16];
    lp[0] = v0; lp[1] = v1;
    __syncthreads();
    f32x4 acc[4][2];
#pragma unroll
    for (int i = 0; i < 4; ++i)
#pragma unroll
        for (int j = 0; j < 2; ++j) acc[i][j] = (f32x4)0.f;
#pragma unroll
    for (int ks = 0; ks < 2; ++ks) {
        short8 a[4];
#pragma unroll
        for (int mt = 0; mt < 4; ++mt)
            a[mt] = *(const short8*)&xs[mt * 16 + l15][ks * 32 + qq * 8];
#pragma unroll
        for (int nt = 0; nt < 2; ++nt) {
            short8 b = *(const short8*)(w2t + (size_t)(wid * 32 + nt * 16 + l15) * 64 + ks * 32 + qq * 8);
#pragma unroll
            for (int mt = 0; mt < 4; ++mt)
                acc[mt][nt] = __builtin_amdgcn_mfma_f32_16x16x32_bf16(a[mt], b, acc[mt][nt], 0, 0, 0);
        }
    }
#pragma unroll
    for (int mt = 0; mt < 4; ++mt) {
        int node = row0 + mt * 16 + qq * 4;
#pragma unroll
        for (int nt = 0; nt < 2; ++nt) {
            int col = wid * 32 + nt * 16 + l15;
#pragma unroll
            for (int rr = 0; rr < 4; ++rr) {
                if (node + rr < NN)
                    h2[(size_t)(node + rr) * 128 + col] = f2b(acc[mt][nt][rr]);
            }
        }
    }
}

// ---------------- alpha dots, layer 1 (att weights fp32)
__global__ __launch_bounds__(256) void kalpha1(const ushort_t* __restrict__ h1,
                                               const float* __restrict__ aw_s,
                                               const float* __restrict__ aw_d,
                                               float* __restrict__ als, float* __restrict__ ald) {
    int tid = blockIdx.x * 256 + threadIdx.x;
    if (tid >= NN * 8) return;
    int n = tid >> 3, h = tid & 7;
    uint4 hv = *(const uint4*)(h1 + (size_t)n * 64 + h * 8);
    const ushort_t* hp = (const ushort_t*)&hv;
    float ss = 0.f, dd = 0.f;
#pragma unroll
    for (int c = 0; c < 8; ++c) {
        float v = b2f(hp[c]);
        ss += v * aw_s[h * 8 + c];
        dd += v * aw_d[h * 8 + c];
    }
    als[tid] = ss;
    ald[tid] = dd;
}

// ---------------- alpha dots, layer 2 (16 channels/head)
__global__ __launch_bounds__(256) void kalpha2(const ushort_t* __restrict__ h2,
                                               const float* __restrict__ aw_s,
                                               const float* __restrict__ aw_d,
                                               float* __restrict__ als, float* __restrict__ ald) {
    int tid = blockIdx.x * 256 + threadIdx.x;
    if (tid >= NN * 8) return;
    int n = tid >> 3, h = tid & 7;
    uint4 v0 = *(const uint4*)(h2 + (size_t)n * 128 + h * 16);
    uint4 v1 = *(const uint4*)(h2 + (size_t)n * 128 + h * 16 + 8);
    const ushort_t* p0 = (const ushort_t*)&v0;
    const ushort_t* p1 = (const ushort_t*)&v1;
    float ss = 0.f, dd = 0.f;
#pragma unroll
    for (int c = 0; c < 8; ++c) {
        float v = b2f(p0[c]);
        ss += v * aw_s[h * 16 + c];
        dd += v * aw_d[h * 16 + c];
    }
#pragma unroll
    for (int c = 0; c < 8; ++c) {
        float v = b2f(p1[c]);
        ss += v * aw_s[h * 16 + 8 + c];
        dd += v * aw_d[h * 16 + 8 + c];
    }
    als[tid] = ss;
    ald[tid] = dd;
}

// ---------------- softmax denominator: one thread per (edge, head)
__global__ __launch_bounds__(256) void kdenom(const int* __restrict__ ei,
                                              const float* __restrict__ als,
                                              const float* __restrict__ ald,
                                              float* __restrict__ den) {
    int tid = blockIdx.x * 256 + threadIdx.x;
    if (tid >= ET * 8) return;
    int e = tid >> 3, h = tid & 7;
    int src, dst;
    if (e < EE) { src = ei[e]; dst = ei[EE + e]; }
    else { src = e - EE; dst = src; }
    float s = als[src * 8 + h] + ald[dst * 8 + h];
    s = (s >= 0.f) ? s : 0.2f * s;
    atomicAdd(&den[dst * 8 + h], __expf(s));
}

// ---------------- layer-1 aggregation: one thread per (edge, head), 8 channels
__global__ __launch_bounds__(256) void kagg1(const int* __restrict__ ei,
                                             const float* __restrict__ als,
                                             const float* __restrict__ ald,
                                             const float* __restrict__ den,
                                             const ushort_t* __restrict__ h1,
                                             float* __restrict__ acc) {
    int tid = blockIdx.x * 256 + threadIdx.x;
    if (tid >= ET * 8) return;
    int e = tid >> 3, h = tid & 7;
    int src, dst;
    if (e < EE) { src = ei[e]; dst = ei[EE + e]; }
    else { src = e - EE; dst = src; }
    float s = als[src * 8 + h] + ald[dst * 8 + h];
    s = (s >= 0.f) ? s : 0.2f * s;
    float w = __expf(s) / den[dst * 8 + h];
    uint4 hv = *(const uint4*)(h1 + (size_t)src * 64 + h * 8);
    const ushort_t* hp = (const ushort_t*)&hv;
    float* ap = acc + (size_t)dst * 64 + h * 8;
#pragma unroll
    for (int c = 0; c < 8; ++c) atomicAdd(ap + c, w * b2f(hp[c]));
}

// ---------------- bias1 + PReLU -> hin (bf16)
__global__ __launch_bounds__(256) void kprelu(const float* __restrict__ acc1,
                                              const float* __restrict__ b1,
                                              const float* __restrict__ pw,
                                              ushort_t* __restrict__ hin) {
    int i = blockIdx.x * 256 + threadIdx.x;  // exactly N*64
    float pwf = pw[0];
    float v = acc1[i] + b1[i & 63];
    v = (v >= 0.f) ? v : pwf * v;
    hin[i] = f2b(v);
}

// ---------------- layer-2 aggregation: one thread per edge, head-mean folded
__global__ __launch_bounds__(256) void kagg2(const int* __restrict__ ei,
                                             const float* __restrict__ als,
                                             const float* __restrict__ ald,
                                             const float* __restrict__ den,
                                             const ushort_t* __restrict__ h2,
                                             float* __restrict__ acc) {
    int e = blockIdx.x * 256 + threadIdx.x;
    if (e >= ET) return;
    int src, dst;
    if (e < EE) { src = ei[e]; dst = ei[EE + e]; }
    else { src = e - EE; dst = src; }
    float o[16];
#pragma unroll
    for (int d = 0; d < 16; ++d) o[d] = 0.f;
#pragma unroll
    for (int h = 0; h < 8; ++h) {
        float s = als[src * 8 + h] + ald[dst * 8 + h];
        s = (s >= 0.f) ? s : 0.2f * s;
        float w = 0.125f * __expf(s) / den[dst * 8 + h];
        uint4 v0 = *(const uint4*)(h2 + (size_t)src * 128 + h * 16);
        uint4 v1 = *(const uint4*)(h2 + (size_t)src * 128 + h * 16 + 8);
        const ushort_t* p0 = (const ushort_t*)&v0;
        const ushort_t* p1 = (const ushort_t*)&v1;
#pragma unroll
        for (int d = 0; d < 8; ++d) {
            o[d] += w * b2f(p0[d]);
            o[8 + d] += w * b2f(p1[d]);
        }
    }
    float* ap = acc + (size_t)dst * 16;
#pragma unroll
    for (int d = 0; d < 16; ++d) atomicAdd(ap + d, o[d]);
}

// ---------------- bias2 + log_softmax -> out (FP32 — reference output dtype)
__global__ __launch_bounds__(256) void klogsm(const float* __restrict__ acc2,
                                              const float* __restrict__ b2,
                                              float* __restrict__ out) {
    int n = blockIdx.x * 256 + threadIdx.x;
    if (n >= NN) return;
    const float4* p = (const float4*)(acc2 + (size_t)n * 16);
    float4 a0 = p[0], a1 = p[1], a2 = p[2], a3 = p[3];
    float v[16] = {a0.x, a0.y, a0.z, a0.w, a1.x, a1.y, a1.z, a1.w,
                   a2.x, a2.y, a2.z, a2.w, a3.x, a3.y, a3.z, a3.w};
#pragma unroll
    for (int d = 0; d < 16; ++d) v[d] += b2[d];
    float m = v[0];
#pragma unroll
    for (int d = 1; d < 16; ++d) m = fmaxf(m, v[d]);
    float sum = 0.f;
#pragma unroll
    for (int d = 0; d < 16; ++d) sum += __expf(v[d] - m);
    float ls = __logf(sum) + m;
    float4* op = (float4*)(out + (size_t)n * 16);
    op[0] = make_float4(v[0] - ls, v[1] - ls, v[2] - ls, v[3] - ls);
    op[1] = make_float4(v[4] - ls, v[5] - ls, v[6] - ls, v[7] - ls);
    op[2] = make_float4(v[8] - ls, v[9] - ls, v[10] - ls, v[11] - ls);
    op[3] = make_float4(v[12] - ls, v[13] - ls, v[14] - ls, v[15] - ls);
}

extern "C" void kernel_launch(void* const* d_in, const int* in_sizes, int n_in,
                              void* d_out, int out_size, void* d_ws, size_t ws_size,
                              hipStream_t stream) {
    // Dtypes (established rounds 0-3): all float tensors fp32, edge_index int32, OUTPUT fp32.
    const float* x    = (const float*)d_in[0];
    const int*   ei   = (const int*)d_in[1];
    const float* W1   = (const float*)d_in[2];
    const float* aws1 = (const float*)d_in[3];
    const float* awd1 = (const float*)d_in[4];
    const float* b1   = (const float*)d_in[5];
    const float* pw   = (const float*)d_in[6];
    const float* W2   = (const float*)d_in[7];
    const float* aws2 = (const float*)d_in[8];
    const float* awd2 = (const float*)d_in[9];
    const float* b2   = (const float*)d_in[10];
    float* out = (float*)d_out;

    // Arena (48.08 MB peak):
    //   [ 0.0 -  3.2M) denom1 (f32, zeroed)
    //   [ 3.2 - 28.8M) acc1 (f32, zeroed)   -> reused as h2 (bf16) after kprelu
    //   [28.8 - 41.6M) h1 (bf16) -> hin -> denom2+acc2 (zeroed mid-stream)
    //   [41.6 - 44.8M) als   [44.8 - 48.0M) ald
    //   [48.0M+) W1T (64KB), W2T (16KB)
    char* ws = (char*)d_ws;
    float*    denom1 = (float*)(ws + 0);
    float*    acc1   = (float*)(ws + 3200000);
    ushort_t* h2     = (ushort_t*)(ws + 3200000);
    ushort_t* h1     = (ushort_t*)(ws + 28800000);
    ushort_t* hin    = (ushort_t*)(ws + 28800000);
    float*    denom2 = (float*)(ws + 28800000);
    float*    acc2   = (float*)(ws + 32000000);
    float*    als    = (float*)(ws + 41600000);
    float*    ald    = (float*)(ws + 44800000);
    ushort_t* W1T    = (ushort_t*)(ws + 48000000);
    ushort_t* W2T    = (ushort_t*)(ws + 48065536);

    hipMemsetAsync(ws, 0, 28800000, stream);  // denom1 + acc1
    ktrans<<<160, 256, 0, stream>>>(W1, W2, W1T, W2T);
    kgemm1<<<1563, 256, 0, stream>>>(x, W1T, h1);
    kalpha1<<<3125, 256, 0, stream>>>(h1, aws1, awd1, als, ald);
    kdenom<<<53125, 256, 0, stream>>>(ei, als, ald, denom1);
    kagg1<<<53125, 256, 0, stream>>>(ei, als, ald, denom1, h1, acc1);
    kprelu<<<25000, 256, 0, stream>>>(acc1, b1, pw, hin);
    kgemm2<<<1563, 256, 0, stream>>>(hin, W2T, h2);
    hipMemsetAsync(ws + 28800000, 0, 9600000, stream);  // denom2 + acc2 (hin dead)
    kalpha2<<<3125, 256, 0, stream>>>(h2, aws2, awd2, als, ald);
    kdenom<<<53125, 256, 0, stream>>>(ei, als, ald, denom2);
    kagg2<<<6641, 256, 0, stream>>>(ei, als, ald, denom2, h2, acc2);
    klogsm<<<391, 256, 0, stream>>>(acc2, b2, out);
}

// Round 5
// 710.833 us; speedup vs baseline: 7.0390x; 7.0390x over previous
//
#include <hip/hip_runtime.h>
#include <hip/hip_bf16.h>

#define NN 100000
#define EE 1600000
#define ET (EE + NN)
#define NB 98  // ceil(NN/1024) scan blocks

typedef unsigned short ushort_t;
typedef short short8 __attribute__((ext_vector_type(8)));
typedef float f32x4 __attribute__((ext_vector_type(4)));

static __device__ __forceinline__ float b2f(unsigned short u) {
    return __uint_as_float(((unsigned int)u) << 16);
}
static __device__ __forceinline__ unsigned short f2b(float f) {
    unsigned int x = __float_as_uint(f);
    return (unsigned short)((x + 0x7fffu + ((x >> 16) & 1u)) >> 16);
}

// ---------------- fp32->bf16 transpose: W1 [512,64] -> W1T [64,512]; W2 [64,128] -> W2T [128,64]
__global__ __launch_bounds__(256) void ktrans(const float* __restrict__ W1,
                                              const float* __restrict__ W2,
                                              ushort_t* __restrict__ W1T,
                                              ushort_t* __restrict__ W2T) {
    int tid = blockIdx.x * 256 + threadIdx.x;
    if (tid < 32768) {
        int k = tid >> 6, c = tid & 63;
        W1T[c * 512 + k] = f2b(W1[tid]);
    } else if (tid < 40960) {
        int t = tid - 32768;
        int k = t >> 7, c = t & 127;
        W2T[c * 64 + k] = f2b(W2[t]);
    }
}

// ---------------- GEMM1: h1[N,64] = x[N,512] @ W1  (fp32 x -> bf16 MFMA, fp32 acc)
__global__ __launch_bounds__(256) void kgemm1(const float* __restrict__ x,
                                              const ushort_t* __restrict__ w1t,
                                              ushort_t* __restrict__ h1) {
    __shared__ __align__(16) ushort_t xs[64][136];
    const int tid = threadIdx.x;
    const int wid = tid >> 6, lane = tid & 63;
    const int l15 = lane & 15, qq = lane >> 4;
    const int row0 = blockIdx.x * 64;
    f32x4 acc[4];
#pragma unroll
    for (int i = 0; i < 4; ++i) acc[i] = (f32x4)0.f;
    for (int kc = 0; kc < 4; ++kc) {
        float4 f[8];
#pragma unroll
        for (int i = 0; i < 8; ++i) {
            int f4i = tid + 256 * i;
            int rr = f4i >> 5;
            int cc = f4i & 31;
            long gr = (long)min(row0 + rr, NN - 1);
            f[i] = *(const float4*)(x + gr * 512 + kc * 128 + cc * 4);
        }
        __syncthreads();
#pragma unroll
        for (int i = 0; i < 8; ++i) {
            int f4i = tid + 256 * i;
            int rr = f4i >> 5, cc = f4i & 31;
            uint2 uu;
            uu.x = ((unsigned)f2b(f[i].y) << 16) | f2b(f[i].x);
            uu.y = ((unsigned)f2b(f[i].w) << 16) | f2b(f[i].z);
            *(uint2*)&xs[rr][cc * 4] = uu;
        }
        __syncthreads();
#pragma unroll
        for (int ks = 0; ks < 4; ++ks) {
            short8 b = *(const short8*)(w1t + (size_t)(wid * 16 + l15) * 512 + kc * 128 + ks * 32 + qq * 8);
#pragma unroll
            for (int mt = 0; mt < 4; ++mt) {
                short8 a = *(const short8*)&xs[mt * 16 + l15][ks * 32 + qq * 8];
                acc[mt] = __builtin_amdgcn_mfma_f32_16x16x32_bf16(a, b, acc[mt], 0, 0, 0);
            }
        }
    }
#pragma unroll
    for (int mt = 0; mt < 4; ++mt) {
        int node = row0 + mt * 16 + qq * 4;
#pragma unroll
        for (int rr = 0; rr < 4; ++rr) {
            if (node + rr < NN)
                h1[(size_t)(node + rr) * 64 + wid * 16 + l15] = f2b(acc[mt][rr]);
        }
    }
}

// ---------------- GEMM2: h2[N,128] = hin[N,64] @ W2  (bf16 in/out)
__global__ __launch_bounds__(256) void kgemm2(const ushort_t* __restrict__ hin,
                                              const ushort_t* __restrict__ w2t,
                                              ushort_t* __restrict__ h2) {
    __shared__ __align__(16) ushort_t xs[64][72];
    const int tid = threadIdx.x;
    const int wid = tid >> 6, lane = tid & 63;
    const int l15 = lane & 15, qq = lane >> 4;
    const int row0 = blockIdx.x * 64;
    const int r = tid >> 2, seg = tid & 3;
    const long grow = (long)min(row0 + r, NN - 1);
    const uint4* gp = (const uint4*)(hin + grow * 64 + seg * 16);
    uint4 v0 = gp[0], v1 = gp[1];
    uint4* lp = (uint4*)&xs[r][seg * 16];
    lp[0] = v0; lp[1] = v1;
    __syncthreads();
    f32x4 acc[4][2];
#pragma unroll
    for (int i = 0; i < 4; ++i)
#pragma unroll
        for (int j = 0; j < 2; ++j) acc[i][j] = (f32x4)0.f;
#pragma unroll
    for (int ks = 0; ks < 2; ++ks) {
        short8 a[4];
#pragma unroll
        for (int mt = 0; mt < 4; ++mt)
            a[mt] = *(const short8*)&xs[mt * 16 + l15][ks * 32 + qq * 8];
#pragma unroll
        for (int nt = 0; nt < 2; ++nt) {
            short8 b = *(const short8*)(w2t + (size_t)(wid * 32 + nt * 16 + l15) * 64 + ks * 32 + qq * 8);
#pragma unroll
            for (int mt = 0; mt < 4; ++mt)
                acc[mt][nt] = __builtin_amdgcn_mfma_f32_16x16x32_bf16(a[mt], b, acc[mt][nt], 0, 0, 0);
        }
    }
#pragma unroll
    for (int mt = 0; mt < 4; ++mt) {
        int node = row0 + mt * 16 + qq * 4;
#pragma unroll
        for (int nt = 0; nt < 2; ++nt) {
            int col = wid * 32 + nt * 16 + l15;
#pragma unroll
            for (int rr = 0; rr < 4; ++rr) {
                if (node + rr < NN)
                    h2[(size_t)(node + rr) * 128 + col] = f2b(acc[mt][nt][rr]);
            }
        }
    }
}

// ================= CSR build =================
__global__ __launch_bounds__(256) void khist(const int* __restrict__ ei, int* __restrict__ cnt) {
    int e = blockIdx.x * 256 + threadIdx.x;
    if (e >= ET) return;
    int dst = (e < EE) ? ei[EE + e] : (e - EE);
    atomicAdd(&cnt[dst], 1);
}

__global__ __launch_bounds__(256) void kredblk(const int* __restrict__ cnt, int* __restrict__ bsum) {
    __shared__ int lds[256];
    int t = threadIdx.x, b = blockIdx.x;
    int base = b * 1024 + t * 4;
    int s = 0;
#pragma unroll
    for (int j = 0; j < 4; ++j) { int i = base + j; if (i < NN) s += cnt[i]; }
    lds[t] = s; __syncthreads();
    for (int off = 128; off > 0; off >>= 1) {
        if (t < off) lds[t] += lds[t + off];
        __syncthreads();
    }
    if (t == 0) bsum[b] = lds[0];
}

__global__ void kscansmall(int* bsum) {
    if (threadIdx.x == 0) {
        int run = 0;
        for (int i = 0; i < NB; ++i) { int v = bsum[i]; bsum[i] = run; run += v; }
    }
}

__global__ __launch_bounds__(256) void kscanfin(const int* __restrict__ cnt, const int* __restrict__ bsum,
                                                int* __restrict__ rowp, int* __restrict__ cur) {
    __shared__ int lds[256];
    int t = threadIdx.x, b = blockIdx.x;
    int base = b * 1024 + t * 4;
    int c[4]; int s = 0;
#pragma unroll
    for (int j = 0; j < 4; ++j) { int i = base + j; c[j] = (i < NN) ? cnt[i] : 0; s += c[j]; }
    lds[t] = s; __syncthreads();
    if (t == 0) { int run = 0; for (int i = 0; i < 256; ++i) { int v = lds[i]; lds[i] = run; run += v; } }
    __syncthreads();
    int off = bsum[b] + lds[t];
#pragma unroll
    for (int j = 0; j < 4; ++j) {
        int i = base + j;
        if (i < NN) { rowp[i] = off; cur[i] = off; off += c[j]; }
    }
    if (b == 0 && t == 0) rowp[NN] = ET;
}

__global__ __launch_bounds__(256) void kscatter(const int* __restrict__ ei, int* __restrict__ cur,
                                                int* __restrict__ srt) {
    int e = blockIdx.x * 256 + threadIdx.x;
    if (e >= ET) return;
    int src, dst;
    if (e < EE) { src = ei[e]; dst = ei[EE + e]; } else { src = dst = e - EE; }
    int pos = atomicAdd(&cur[dst], 1);
    srt[pos] = src;
}

// ================= layer-1 fused agg: softmax-weighted sum + bias + PReLU -> hin (bf16)
// one thread per (dst, head); single pass (num vec + den scalar); alpha dots on the fly
__global__ __launch_bounds__(256) void kagg1(const int* __restrict__ rowp,
                                             const int* __restrict__ srt,
                                             const ushort_t* __restrict__ h1,
                                             const float* __restrict__ aws,
                                             const float* __restrict__ awd,
                                             const float* __restrict__ b1,
                                             const float* __restrict__ pw,
                                             ushort_t* __restrict__ hin) {
    int tid = blockIdx.x * 256 + threadIdx.x;  // exactly N*8
    int n = tid >> 3, h = tid & 7;
    float as_w[8], ad_w[8];
#pragma unroll
    for (int c = 0; c < 8; ++c) { as_w[c] = aws[h * 8 + c]; ad_w[c] = awd[h * 8 + c]; }
    uint4 hd = *(const uint4*)(h1 + (size_t)n * 64 + h * 8);
    const ushort_t* hdp = (const ushort_t*)&hd;
    float ad = 0.f;
#pragma unroll
    for (int c = 0; c < 8; ++c) ad += b2f(hdp[c]) * ad_w[c];
    int j0 = rowp[n], j1 = rowp[n + 1];
    float num[8]; float den = 0.f;
#pragma unroll
    for (int c = 0; c < 8; ++c) num[c] = 0.f;
    for (int j = j0; j < j1; ++j) {
        int s = srt[j];
        uint4 hv = *(const uint4*)(h1 + (size_t)s * 64 + h * 8);
        const ushort_t* hp = (const ushort_t*)&hv;
        float va[8];
#pragma unroll
        for (int c = 0; c < 8; ++c) va[c] = b2f(hp[c]);
        float sc = ad;
#pragma unroll
        for (int c = 0; c < 8; ++c) sc += va[c] * as_w[c];
        sc = (sc >= 0.f) ? sc : 0.2f * sc;
        float w = __expf(sc);
        den += w;
#pragma unroll
        for (int c = 0; c < 8; ++c) num[c] += w * va[c];
    }
    float inv = 1.f / den;  // den > 0 (self-loop guarantees >=1 edge)
    float pwf = pw[0];
    ushort_t o[8];
#pragma unroll
    for (int c = 0; c < 8; ++c) {
        float v = num[c] * inv + b1[h * 8 + c];
        v = (v >= 0.f) ? v : pwf * v;
        o[c] = f2b(v);
    }
    *(uint4*)(hin + (size_t)n * 64 + h * 8) = *(uint4*)o;
}

// ================= layer-2 fused agg: softmax-weighted sum + head-mean + bias + log_softmax -> out (fp32)
// one thread per (dst, head); LDS reduce over heads; 32 nodes per block
__global__ __launch_bounds__(256) void kagg2(const int* __restrict__ rowp,
                                             const int* __restrict__ srt,
                                             const ushort_t* __restrict__ h2,
                                             const float* __restrict__ aws,
                                             const float* __restrict__ awd,
                                             const float* __restrict__ b2,
                                             float* __restrict__ out) {
    __shared__ float red[32][17];
    int t = threadIdx.x;
    int nl = t >> 3, h = t & 7;
    int n = blockIdx.x * 32 + nl;  // grid 3125*32 == NN exactly
    for (int i = t; i < 32 * 17; i += 256) ((float*)red)[i] = 0.f;
    __syncthreads();
    float as_w[16], ad_w[16];
#pragma unroll
    for (int c = 0; c < 16; ++c) { as_w[c] = aws[h * 16 + c]; ad_w[c] = awd[h * 16 + c]; }
    uint4 d0 = *(const uint4*)(h2 + (size_t)n * 128 + h * 16);
    uint4 d1 = *(const uint4*)(h2 + (size_t)n * 128 + h * 16 + 8);
    const ushort_t* dp0 = (const ushort_t*)&d0;
    const ushort_t* dp1 = (const ushort_t*)&d1;
    float ad = 0.f;
#pragma unroll
    for (int c = 0; c < 8; ++c) { ad += b2f(dp0[c]) * ad_w[c]; ad += b2f(dp1[c]) * ad_w[8 + c]; }
    int j0 = rowp[n], j1 = rowp[n + 1];
    float num[16]; float den = 0.f;
#pragma unroll
    for (int c = 0; c < 16; ++c) num[c] = 0.f;
    for (int j = j0; j < j1; ++j) {
        int s = srt[j];
        uint4 v0 = *(const uint4*)(h2 + (size_t)s * 128 + h * 16);
        uint4 v1 = *(const uint4*)(h2 + (size_t)s * 128 + h * 16 + 8);
        const ushort_t* p0 = (const ushort_t*)&v0;
        const ushort_t* p1 = (const ushort_t*)&v1;
        float va[16];
#pragma unroll
        for (int c = 0; c < 8; ++c) { va[c] = b2f(p0[c]); va[8 + c] = b2f(p1[c]); }
        float sc = ad;
#pragma unroll
        for (int c = 0; c < 16; ++c) sc += va[c] * as_w[c];
        sc = (sc >= 0.f) ? sc : 0.2f * sc;
        float w = __expf(sc);
        den += w;
#pragma unroll
        for (int c = 0; c < 16; ++c) num[c] += w * va[c];
    }
    float sden = 0.125f / den;
#pragma unroll
    for (int k = 0; k < 16; ++k) {
        int c = (h * 2 + k) & 15;  // stagger: no same-address contention within a node
        atomicAdd(&red[nl][c], num[c] * sden);
    }
    __syncthreads();
    if (t < 32) {
        float v[16];
#pragma unroll
        for (int d = 0; d < 16; ++d) v[d] = red[t][d] + b2[d];
        float m = v[0];
#pragma unroll
        for (int d = 1; d < 16; ++d) m = fmaxf(m, v[d]);
        float sum = 0.f;
#pragma unroll
        for (int d = 0; d < 16; ++d) sum += __expf(v[d] - m);
        float ls = __logf(sum) + m;
        float* op = out + (size_t)(blockIdx.x * 32 + t) * 16;
#pragma unroll
        for (int d = 0; d < 16; ++d) op[d] = v[d] - ls;
    }
}

extern "C" void kernel_launch(void* const* d_in, const int* in_sizes, int n_in,
                              void* d_out, int out_size, void* d_ws, size_t ws_size,
                              hipStream_t stream) {
    const float* x    = (const float*)d_in[0];
    const int*   ei   = (const int*)d_in[1];
    const float* W1   = (const float*)d_in[2];
    const float* aws1 = (const float*)d_in[3];
    const float* awd1 = (const float*)d_in[4];
    const float* b1   = (const float*)d_in[5];
    const float* pw   = (const float*)d_in[6];
    const float* W2   = (const float*)d_in[7];
    const float* aws2 = (const float*)d_in[8];
    const float* awd2 = (const float*)d_in[9];
    const float* b2   = (const float*)d_in[10];
    float* out = (float*)d_out;

    // Arena (46.5 MB peak):
    //   [ 0.0 -  6.8M) sorted_src (ET int)
    //   [ 6.8 -  7.2M) row_ptr (N+1 int)
    //   [ 7.2 -  7.6M) cnt/cursor (N int, zeroed)
    //   [ 7.6M +512  ) bsum (NB int)
    //   [ 8.0 - 20.8M) hin (bf16)          [written by kagg1, read by kgemm2]
    //   [20.8 - 33.6M) h1 (bf16)           [dead after kagg1]
    //   [20.8 - 46.4M) h2 (bf16)           [overlaps dead h1; written by kgemm2]
    //   [46.4M+) W1T (64KB), W2T (16KB)
    char* ws = (char*)d_ws;
    int*      srt  = (int*)(ws + 0);
    int*      rowp = (int*)(ws + 6800000);
    int*      cnt  = (int*)(ws + 7200256);
    int*      bsum = (int*)(ws + 7600384);
    ushort_t* hin  = (ushort_t*)(ws + 8000000);
    ushort_t* h1   = (ushort_t*)(ws + 20800000);
    ushort_t* h2   = (ushort_t*)(ws + 20800000);
    ushort_t* W1T  = (ushort_t*)(ws + 46400000);
    ushort_t* W2T  = (ushort_t*)(ws + 46465536);

    hipMemsetAsync(cnt, 0, 400000, stream);
    ktrans<<<160, 256, 0, stream>>>(W1, W2, W1T, W2T);
    kgemm1<<<1563, 256, 0, stream>>>(x, W1T, h1);
    khist<<<6641, 256, 0, stream>>>(ei, cnt);
    kredblk<<<NB, 256, 0, stream>>>(cnt, bsum);
    kscansmall<<<1, 64, 0, stream>>>(bsum);
    kscanfin<<<NB, 256, 0, stream>>>(cnt, bsum, rowp, cnt /*cursor shares cnt*/);
    kscatter<<<6641, 256, 0, stream>>>(ei, cnt, srt);
    kagg1<<<3125, 256, 0, stream>>>(rowp, srt, h1, aws1, awd1, b1, pw, hin);
    kgemm2<<<1563, 256, 0, stream>>>(hin, W2T, h2);
    kagg2<<<3125, 256, 0, stream>>>(rowp, srt, h2, aws2, awd2, b2, out);
}